// Round 4
// baseline (240.540 us; speedup 1.0000x reference)
//
#include <hip/hip_runtime.h>

typedef __bf16 bf16x8 __attribute__((ext_vector_type(8)));
typedef float f32x4 __attribute__((ext_vector_type(4)));
typedef unsigned short u16x8 __attribute__((ext_vector_type(8)));
typedef short s16x4 __attribute__((ext_vector_type(4)));

__device__ __forceinline__ unsigned short f2b(float f) {
    union { float f; unsigned u; } v; v.f = f;
    unsigned r = (v.u + 0x7fffu + ((v.u >> 16) & 1u)) >> 16;
    return (unsigned short)r;
}

__device__ __forceinline__ void load_lds16(const void* g, void* l) {
    __builtin_amdgcn_global_load_lds(
        (const __attribute__((address_space(1))) unsigned int*)g,
        (__attribute__((address_space(3))) unsigned int*)l,
        16, 0, 0);
}

// ---------------- f32 -> bf16 conversion ----------------
__global__ void cvt_kernel(const float* __restrict__ in, unsigned short* __restrict__ out, int n4) {
    int i = blockIdx.x * 256 + threadIdx.x;
    if (i < n4) {
        f32x4 v = ((const f32x4*)in)[i];
        s16x4 o;
        o.x = (short)f2b(v.x);
        o.y = (short)f2b(v.y);
        o.z = (short)f2b(v.z);
        o.w = (short)f2b(v.w);
        ((s16x4*)out)[i] = o;
    }
}

// ---------------- generic bf16 GEMM: C[M,N] = A[M,K] * B[N,K]^T + bias ----------------
// BK=128, single-buffered LDS (2 blocks/CU anti-phase), 4 waves in 2x2,
// per-wave (BM/2)x(BN/2) sub-tile. XCD-bijective block swizzle.
// EPI: 0 = bf16 out, 1 = f32 out, 2 = gelu(exact) -> bf16 out
template <int BM, int BN, int EPI>
__global__ __launch_bounds__(256, 2)
void gemm_bt(const unsigned short* __restrict__ A, const unsigned short* __restrict__ Bm,
             const float* __restrict__ bias, void* __restrict__ Cout,
             int M, int N, int K) {
    constexpr int BK = 128;
    constexpr int MR = BM / 32;                    // 16-row frags per wave
    constexpr int NR = BN / 32;                    // 16-col frags per wave
    constexpr int ACH = BM / 4, BCH = BN / 4, TCH = ACH + BCH;  // 1KB chunks (4 rows x 256B)
    __shared__ unsigned short As[BM * BK];
    __shared__ unsigned short Bs[BN * BK];
    const int tid = threadIdx.x, lane = tid & 63, wid = tid >> 6;
    const int l15 = lane & 15, lq = lane >> 4;
    const int lr = lane >> 4, lc = (lane & 15) * 8;  // staging: 4 rows x 16 chunks of 16B

    // XCD-bijective swizzle (nwg % 8 == 0 for all launches below)
    const int nwg = gridDim.x * gridDim.y;
    int bid = blockIdx.y * gridDim.x + blockIdx.x;
    bid = (bid & 7) * (nwg >> 3) + (bid >> 3);
    const int bx = bid % gridDim.x, by = bid / gridDim.x;
    const int m0 = by * BM, n0 = bx * BN;

    const int wm0 = (wid >> 1) * (BM / 2);
    const int wn0 = (wid & 1) * (BN / 2);

    f32x4 acc[MR][NR];
#pragma unroll
    for (int i = 0; i < MR; i++)
#pragma unroll
        for (int j = 0; j < NR; j++) acc[i][j] = 0.0f;

    const int nkt = K / BK;
    for (int kt = 0; kt < nkt; ++kt) {
        const int kb = kt * BK;
        // stage A[BM][128] and B[BN][128]: 1KB chunks, round-robin over waves
#pragma unroll
        for (int i = 0; i < TCH / 4; ++i) {
            const int ch = wid + i * 4;
            if (ch < ACH) {
                load_lds16(A + (size_t)(m0 + ch * 4 + lr) * K + kb + lc,
                           (char*)As + ch * 1024);
            } else {
                load_lds16(Bm + (size_t)(n0 + (ch - ACH) * 4 + lr) * K + kb + lc,
                           (char*)Bs + (ch - ACH) * 1024);
            }
        }
        __syncthreads();      // drains vmcnt(0): tile ready
#pragma unroll
        for (int kc = 0; kc < 4; ++kc) {
            bf16x8 af[MR], bf[NR];
#pragma unroll
            for (int mi = 0; mi < MR; mi++)
                af[mi] = *(const bf16x8*)&As[(wm0 + mi * 16 + l15) * BK + kc * 32 + lq * 8];
#pragma unroll
            for (int ni = 0; ni < NR; ni++)
                bf[ni] = *(const bf16x8*)&Bs[(wn0 + ni * 16 + l15) * BK + kc * 32 + lq * 8];
#pragma unroll
            for (int mi = 0; mi < MR; mi++)
#pragma unroll
                for (int ni = 0; ni < NR; ni++)
                    acc[mi][ni] = __builtin_amdgcn_mfma_f32_16x16x32_bf16(af[mi], bf[ni], acc[mi][ni], 0, 0, 0);
        }
        __syncthreads();      // guard LDS reuse
    }
    // epilogue
#pragma unroll
    for (int mi = 0; mi < MR; mi++) {
#pragma unroll
        for (int ni = 0; ni < NR; ni++) {
            int col = n0 + wn0 + ni * 16 + l15;
            float bv = bias[col];
#pragma unroll
            for (int r = 0; r < 4; r++) {
                int row = m0 + wm0 + mi * 16 + lq * 4 + r;
                float v = acc[mi][ni][r] + bv;
                if constexpr (EPI == 2) {
                    v = 0.5f * v * (1.0f + erff(v * 0.7071067811865475f));
                }
                if constexpr (EPI == 1) {
                    ((float*)Cout)[(size_t)row * N + col] = v;
                } else {
                    ((unsigned short*)Cout)[(size_t)row * N + col] = f2b(v);
                }
            }
        }
    }
}

// ---------------- flash attention ----------------
// qkv: [B*L, 2304] bf16 (q at +0, k at +768, v at +1536, per-head stride 96)
// bias: [B, L, L] f32 ; out: [B*L, 768] bf16
__global__ __launch_bounds__(256, 2)
void attn_kernel(const unsigned short* __restrict__ qkv,
                 const float* __restrict__ bias,
                 unsigned short* __restrict__ out) {
    const int L = 1024, TD = 2304, HD = 96;
    const int qt = blockIdx.x, h = blockIdx.y, b = blockIdx.z;
    const int tid = threadIdx.x, lane = tid & 63, wid = tid >> 6;
    const int l15 = lane & 15, lq = lane >> 4;
    const int q0 = qt * 64;
    const float scale = 0.10206207261596576f; // 1/sqrt(96)

    __shared__ unsigned short Ks[64][104];
    __shared__ unsigned short Vt[96][72];
    __shared__ unsigned short Ps[4][16][72];

    // Q fragments stay in registers for the whole block
    bf16x8 qf[3];
    const int qrow = q0 + wid * 16 + l15;
#pragma unroll
    for (int kc = 0; kc < 3; kc++)
        qf[kc] = *(const bf16x8*)(qkv + (size_t)(b * L + qrow) * TD + h * HD + kc * 32 + lq * 8);

    f32x4 o[6];
#pragma unroll
    for (int df = 0; df < 6; df++) o[df] = 0.0f;
    float mrow[4] = {-1e30f, -1e30f, -1e30f, -1e30f};
    float lrow[4] = {0.f, 0.f, 0.f, 0.f};

    for (int kv0 = 0; kv0 < L; kv0 += 64) {
        // stage K tile [64][96]
#pragma unroll
        for (int i = 0; i < 3; i++) {
            int c = i * 256 + tid;          // 0..767
            int row = c / 12, cc = c % 12;  // 12 x 16B chunks per row
            *(f32x4*)&Ks[row][cc * 8] =
                *(const f32x4*)(qkv + (size_t)(b * L + kv0 + row) * TD + 768 + h * HD + cc * 8);
        }
        // stage V transposed: Vt[d][m]
#pragma unroll
        for (int i = 0; i < 3; i++) {
            int dblk = i * 4 + wid;  // 0..11
            int m = lane;
            u16x8 v = *(const u16x8*)(qkv + (size_t)(b * L + kv0 + m) * TD + 1536 + h * HD + dblk * 8);
#pragma unroll
            for (int j = 0; j < 8; j++) Vt[dblk * 8 + j][m] = v[j];
        }
        __syncthreads();

        // S = Q K^T  (wave computes its 16 q-rows x 64 kv-cols)
        f32x4 s[4];
#pragma unroll
        for (int nf = 0; nf < 4; nf++) s[nf] = 0.0f;
#pragma unroll
        for (int kc = 0; kc < 3; kc++) {
#pragma unroll
            for (int nf = 0; nf < 4; nf++) {
                bf16x8 kf = *(const bf16x8*)&Ks[nf * 16 + l15][kc * 32 + lq * 8];
                s[nf] = __builtin_amdgcn_mfma_f32_16x16x32_bf16(qf[kc], kf, s[nf], 0, 0, 0);
            }
        }
        // scale + bias
#pragma unroll
        for (int nf = 0; nf < 4; nf++) {
            int colg = kv0 + nf * 16 + l15;
#pragma unroll
            for (int r = 0; r < 4; r++) {
                int rowg = q0 + wid * 16 + lq * 4 + r;
                s[nf][r] = s[nf][r] * scale + bias[((size_t)b * L + rowg) * L + colg];
            }
        }
        // online softmax (row r of this quarter lives in 16 lanes: xor-reduce 1,2,4,8)
        float pm[4];
#pragma unroll
        for (int r = 0; r < 4; r++) {
            float mx = fmaxf(fmaxf(s[0][r], s[1][r]), fmaxf(s[2][r], s[3][r]));
#pragma unroll
            for (int d = 1; d < 16; d <<= 1) mx = fmaxf(mx, __shfl_xor(mx, d, 64));
            pm[r] = mx;
        }
        float alpha[4];
#pragma unroll
        for (int r = 0; r < 4; r++) {
            float mn = fmaxf(mrow[r], pm[r]);
            alpha[r] = __expf(mrow[r] - mn);
            mrow[r] = mn;
        }
        float rs[4] = {0.f, 0.f, 0.f, 0.f};
#pragma unroll
        for (int nf = 0; nf < 4; nf++)
#pragma unroll
            for (int r = 0; r < 4; r++) {
                float p = __expf(s[nf][r] - mrow[r]);
                s[nf][r] = p;
                rs[r] += p;
            }
#pragma unroll
        for (int r = 0; r < 4; r++) {
#pragma unroll
            for (int d = 1; d < 16; d <<= 1) rs[r] += __shfl_xor(rs[r], d, 64);
            lrow[r] = lrow[r] * alpha[r] + rs[r];
        }
        // P -> LDS (C-layout -> A-layout re-shape), bf16
#pragma unroll
        for (int nf = 0; nf < 4; nf++)
#pragma unroll
            for (int r = 0; r < 4; r++)
                Ps[wid][lq * 4 + r][nf * 16 + l15] = f2b(s[nf][r]);
        // rescale O
#pragma unroll
        for (int df = 0; df < 6; df++)
#pragma unroll
            for (int r = 0; r < 4; r++) o[df][r] *= alpha[r];
        // make P writes visible to the wave's own reads
        asm volatile("s_waitcnt lgkmcnt(0)" ::: "memory");
        // O += P V
#pragma unroll
        for (int kc = 0; kc < 2; kc++) {
            bf16x8 pf = *(const bf16x8*)&Ps[wid][l15][kc * 32 + lq * 8];
#pragma unroll
            for (int df = 0; df < 6; df++) {
                bf16x8 vf = *(const bf16x8*)&Vt[df * 16 + l15][kc * 32 + lq * 8];
                o[df] = __builtin_amdgcn_mfma_f32_16x16x32_bf16(pf, vf, o[df], 0, 0, 0);
            }
        }
        __syncthreads();
    }
    // normalize + write [B*L, 768]
#pragma unroll
    for (int r = 0; r < 4; r++) {
        float inv = 1.0f / lrow[r];
        int rowg = q0 + wid * 16 + lq * 4 + r;
#pragma unroll
        for (int df = 0; df < 6; df++)
            out[((size_t)b * L + rowg) * 768 + h * 96 + df * 16 + l15] = f2b(o[df][r] * inv);
    }
}

// ---------------- residual + layernorm ----------------
// out_f = LN(x + res) (f32), optionally also bf16 copy
template <int WRITE_B>
__global__ __launch_bounds__(256, 4)
void ln_kernel(const float* __restrict__ x, const float* __restrict__ res,
               const float* __restrict__ g, const float* __restrict__ bvec,
               float* __restrict__ outf, unsigned short* __restrict__ outb) {
    const int Dm = 768;
    int row = blockIdx.x;
    const float* xr = x + (size_t)row * Dm;
    const float* rr = res + (size_t)row * Dm;
    int tid = threadIdx.x;
    float v[3];
    float sum = 0.f, sq = 0.f;
#pragma unroll
    for (int j = 0; j < 3; j++) {
        int i = tid + j * 256;
        float t = xr[i] + rr[i];
        v[j] = t;
        sum += t;
        sq += t * t;
    }
#pragma unroll
    for (int d = 1; d < 64; d <<= 1) {
        sum += __shfl_xor(sum, d, 64);
        sq += __shfl_xor(sq, d, 64);
    }
    __shared__ float ps[8];
    int lane = tid & 63, wid = tid >> 6;
    if (lane == 0) { ps[wid] = sum; ps[wid + 4] = sq; }
    __syncthreads();
    sum = ps[0] + ps[1] + ps[2] + ps[3];
    sq = ps[4] + ps[5] + ps[6] + ps[7];
    float mu = sum * (1.0f / 768.0f);
    float var = sq * (1.0f / 768.0f) - mu * mu;
    float rsg = rsqrtf(var + 1e-5f);
#pragma unroll
    for (int j = 0; j < 3; j++) {
        int i = tid + j * 256;
        float o = (v[j] - mu) * rsg * g[i] + bvec[i];
        outf[(size_t)row * Dm + i] = o;
        if constexpr (WRITE_B) outb[(size_t)row * Dm + i] = f2b(o);
    }
}

// ---------------- launch ----------------
extern "C" void kernel_launch(void* const* d_in, const int* in_sizes, int n_in,
                              void* d_out, int out_size, void* d_ws, size_t ws_size,
                              hipStream_t stream) {
    (void)in_sizes; (void)n_in; (void)out_size; (void)ws_size;
    const float* x         = (const float*)d_in[0];
    const float* attn_bias = (const float*)d_in[1];
    const float* in_proj_w = (const float*)d_in[2];
    const float* in_proj_b = (const float*)d_in[3];
    const float* out_w     = (const float*)d_in[4];
    const float* out_b     = (const float*)d_in[5];
    const float* ff1_w     = (const float*)d_in[6];
    const float* ff1_b     = (const float*)d_in[7];
    const float* ff2_w     = (const float*)d_in[8];
    const float* ff2_b     = (const float*)d_in[9];
    const float* ln1_g     = (const float*)d_in[10];
    const float* ln1_b     = (const float*)d_in[11];
    const float* ln2_g     = (const float*)d_in[12];
    const float* ln2_b     = (const float*)d_in[13];

    const int NTOK = 4096;        // B*L
    char* ws = (char*)d_ws;
    size_t off = 0;
    auto alloc = [&](size_t bytes) { void* p = ws + off; off += (bytes + 255) & ~(size_t)255; return p; };
    unsigned short* xb    = (unsigned short*)alloc((size_t)NTOK * 768 * 2);
    unsigned short* wqkv  = (unsigned short*)alloc((size_t)2304 * 768 * 2);
    unsigned short* wout  = (unsigned short*)alloc((size_t)768 * 768 * 2);
    unsigned short* wff1  = (unsigned short*)alloc((size_t)2048 * 768 * 2);
    unsigned short* wff2  = (unsigned short*)alloc((size_t)768 * 2048 * 2);
    unsigned short* qkvb  = (unsigned short*)alloc((size_t)NTOK * 2304 * 2);
    unsigned short* attnb = (unsigned short*)alloc((size_t)NTOK * 768 * 2);
    float*          aproj = (float*)alloc((size_t)NTOK * 768 * 4);
    float*          x1f   = (float*)alloc((size_t)NTOK * 768 * 4);
    unsigned short* x1b   = (unsigned short*)alloc((size_t)NTOK * 768 * 2);
    // aliases (lifetimes are disjoint):
    unsigned short* h1b  = qkvb;   // [4096,2048] bf16 (16.8MB) fits in qkv region (18.9MB)
    float*          ff2o = aproj;  // [4096,768] f32, aproj is dead after LN1

    // f32 -> bf16 conversions
    cvt_kernel<<<dim3((NTOK * 768 / 4) / 256), 256, 0, stream>>>(x, xb, NTOK * 768 / 4);
    cvt_kernel<<<dim3((2304 * 768 / 4) / 256), 256, 0, stream>>>(in_proj_w, wqkv, 2304 * 768 / 4);
    cvt_kernel<<<dim3((768 * 768 / 4) / 256), 256, 0, stream>>>(out_w, wout, 768 * 768 / 4);
    cvt_kernel<<<dim3((2048 * 768 / 4) / 256), 256, 0, stream>>>(ff1_w, wff1, 2048 * 768 / 4);
    cvt_kernel<<<dim3((768 * 2048 / 4) / 256), 256, 0, stream>>>(ff2_w, wff2, 768 * 2048 / 4);

    // qkv = x @ in_proj_w^T + b        [4096, 2304] bf16   grid 18x32 = 576
    gemm_bt<128, 128, 0><<<dim3(2304 / 128, NTOK / 128), 256, 0, stream>>>(xb, wqkv, in_proj_b, qkvb, NTOK, 2304, 768);
    // attention                         [4096, 768] bf16
    attn_kernel<<<dim3(16, 8, 4), 256, 0, stream>>>(qkvb, attn_bias, attnb);
    // attn @ out_w^T + b               [4096, 768] f32     grid 12x64 = 768
    gemm_bt<64, 64, 1><<<dim3(768 / 64, NTOK / 64), 256, 0, stream>>>(attnb, wout, out_b, aproj, NTOK, 768, 768);
    // x1 = LN1(x + aproj)              f32 + bf16
    ln_kernel<1><<<dim3(NTOK), 256, 0, stream>>>(x, aproj, ln1_g, ln1_b, x1f, x1b);
    // h = gelu(x1 @ ff1^T + b)         [4096, 2048] bf16   grid 16x32 = 512
    gemm_bt<128, 128, 2><<<dim3(2048 / 128, NTOK / 128), 256, 0, stream>>>(x1b, wff1, ff1_b, h1b, NTOK, 2048, 768);
    // ff2 = h @ ff2^T + b              [4096, 768] f32     grid 12x64 = 768
    gemm_bt<64, 64, 1><<<dim3(768 / 64, NTOK / 64), 256, 0, stream>>>(h1b, wff2, ff2_b, ff2o, NTOK, 768, 2048);
    // out = LN2(x1 + ff2)              f32 -> d_out
    ln_kernel<0><<<dim3(NTOK), 256, 0, stream>>>(x1f, ff2o, ln2_g, ln2_b, (float*)d_out, nullptr);
}

// Round 5
// 178.578 us; speedup vs baseline: 1.3470x; 1.3470x over previous
//
#include <hip/hip_runtime.h>

typedef __bf16 bf16x8 __attribute__((ext_vector_type(8)));
typedef float f32x4 __attribute__((ext_vector_type(4)));
typedef unsigned short u16x8 __attribute__((ext_vector_type(8)));
typedef short s16x4 __attribute__((ext_vector_type(4)));

__device__ __forceinline__ unsigned short f2b(float f) {
    union { float f; unsigned u; } v; v.f = f;
    unsigned r = (v.u + 0x7fffu + ((v.u >> 16) & 1u)) >> 16;
    return (unsigned short)r;
}

__device__ __forceinline__ void load_lds16(const void* g, void* l) {
    __builtin_amdgcn_global_load_lds(
        (const __attribute__((address_space(1))) unsigned int*)g,
        (__attribute__((address_space(3))) unsigned int*)l,
        16, 0, 0);
}

// ---------------- f32 -> bf16 conversion ----------------
__global__ void cvt_kernel(const float* __restrict__ in, unsigned short* __restrict__ out, int n4) {
    int i = blockIdx.x * 256 + threadIdx.x;
    if (i < n4) {
        f32x4 v = ((const f32x4*)in)[i];
        s16x4 o;
        o.x = (short)f2b(v.x);
        o.y = (short)f2b(v.y);
        o.z = (short)f2b(v.z);
        o.w = (short)f2b(v.w);
        ((s16x4*)out)[i] = o;
    }
}

// ---------------- pipelined bf16 GEMM: C[M,N] = A[M,K] * B[N,K]^T + bias ----------------
// 3-deep K-tile pipeline, counted vmcnt (never drained to 0 in steady state),
// raw s_barrier, T2 XOR-swizzled LDS (pre-swizzled glds source + swizzled ds_read).
// 8 waves (512 thr) in 2M x 4N; wave tile = 64 x (BN/4); BK = 64.
// EPI: 0 = bf16 out, 1 = f32 out, 2 = gelu(exact) -> bf16 out
template <int BM, int BN, int EPI>
__global__ __launch_bounds__(512, 2)
void gemm_pipe(const unsigned short* __restrict__ A, const unsigned short* __restrict__ Bm,
               const float* __restrict__ bias, void* __restrict__ Cout,
               int M, int N, int K) {
    constexpr int ACH = BM / 8;            // 1KB chunks in A K-tile (8 rows x 128B)
    constexpr int TC  = (BM + BN) / 8;     // total chunks per K-tile
    constexpr int CPW = TC / 8;            // chunks per wave
    constexpr int MR = 4;                  // 4 x 16 rows per wave
    constexpr int NR = BN / 64;            // (BN/4)/16 col frags per wave
    __shared__ unsigned short As[3][BM * 64];
    __shared__ unsigned short Bs[3][BN * 64];
    const int tid = threadIdx.x, lane = tid & 63, wid = tid >> 6;
    const int l15 = lane & 15, lq = lane >> 4;
    const int wr = wid >> 2, wc = wid & 3;

    // XCD-bijective swizzle (all grids below have nwg % 8 == 0)
    const int nwg = gridDim.x * gridDim.y;
    int bid = blockIdx.y * gridDim.x + blockIdx.x;
    bid = (bid & 7) * (nwg >> 3) + (bid >> 3);
    const int bx = bid % gridDim.x, by = bid / gridDim.x;
    const int m0 = by * BM, n0 = bx * BN;

    // staging: chunk = 8 rows x 128B; lane -> row lane>>3, col-slot lane&7.
    // source col pre-swizzled so LDS linear (row, s) holds global (row, s^(row&7)).
    const int srow = lane >> 3;
    const int scol = ((lane & 7) ^ srow) * 8;   // element offset (16B units * 8 elems)

    f32x4 acc[MR][NR];
#pragma unroll
    for (int i = 0; i < MR; i++)
#pragma unroll
        for (int j = 0; j < NR; j++) acc[i][j] = 0.0f;

    auto stage = [&](int buf, int kt) {
        const int kb = kt * 64;
#pragma unroll
        for (int i = 0; i < CPW; ++i) {
            const int c = wid * CPW + i;
            if (c < ACH) {
                load_lds16(A + (size_t)(m0 + c * 8 + srow) * K + kb + scol,
                           (char*)As[buf] + c * 1024);
            } else {
                load_lds16(Bm + (size_t)(n0 + (c - ACH) * 8 + srow) * K + kb + scol,
                           (char*)Bs[buf] + (c - ACH) * 1024);
            }
        }
    };

    auto compute = [&](int buf) {
#pragma unroll
        for (int kc = 0; kc < 2; ++kc) {
            const int cb = kc * 64;             // col byte base within 128B row
            const int sw = (l15 & 7) << 4;      // read-side XOR swizzle
            bf16x8 af[MR], bf[NR];
#pragma unroll
            for (int mi = 0; mi < MR; mi++) {
                const int row = wr * 64 + mi * 16 + l15;
                af[mi] = *(const bf16x8*)((const char*)As[buf] + row * 128 + ((cb + lq * 16) ^ sw));
            }
#pragma unroll
            for (int ni = 0; ni < NR; ni++) {
                const int row = wc * (BN / 4) + ni * 16 + l15;
                bf[ni] = *(const bf16x8*)((const char*)Bs[buf] + row * 128 + ((cb + lq * 16) ^ sw));
            }
#pragma unroll
            for (int mi = 0; mi < MR; mi++)
#pragma unroll
                for (int ni = 0; ni < NR; ni++)
                    acc[mi][ni] = __builtin_amdgcn_mfma_f32_16x16x32_bf16(af[mi], bf[ni], acc[mi][ni], 0, 0, 0);
        }
    };

    const int nkt = K / 64;   // >= 3 for all our shapes
    stage(0, 0);
    stage(1, 1);
    stage(2, 2);
    int cur = 0;
    for (int t = 0; t < nkt; ++t) {
        // wait until tile t's own loads are complete (6 glds per tile per wave)
        if (t <= nkt - 3)      asm volatile("s_waitcnt vmcnt(12)" ::: "memory");
        else if (t == nkt - 2) asm volatile("s_waitcnt vmcnt(6)" ::: "memory");
        else                   asm volatile("s_waitcnt vmcnt(0)" ::: "memory");
        __builtin_amdgcn_s_barrier();       // now ALL waves' tile-t loads are done
        asm volatile("" ::: "memory");
        compute(cur);
        asm volatile("" ::: "memory");
        __builtin_amdgcn_s_barrier();       // all waves done reading buf[cur]
        if (t + 3 < nkt) stage(cur, t + 3); // reuse buffer, loads fly across 2 phases
        cur = (cur == 2) ? 0 : cur + 1;
    }

    // epilogue
#pragma unroll
    for (int mi = 0; mi < MR; mi++) {
#pragma unroll
        for (int ni = 0; ni < NR; ni++) {
            const int col = n0 + wc * (BN / 4) + ni * 16 + l15;
            const float bv = bias[col];
#pragma unroll
            for (int r = 0; r < 4; r++) {
                const int row = m0 + wr * 64 + mi * 16 + lq * 4 + r;
                float v = acc[mi][ni][r] + bv;
                if constexpr (EPI == 2) {
                    v = 0.5f * v * (1.0f + erff(v * 0.7071067811865475f));
                }
                if constexpr (EPI == 1) {
                    ((float*)Cout)[(size_t)row * N + col] = v;
                } else {
                    ((unsigned short*)Cout)[(size_t)row * N + col] = f2b(v);
                }
            }
        }
    }
}

// ---------------- flash attention ----------------
// qkv: [B*L, 2304] bf16 (q at +0, k at +768, v at +1536, per-head stride 96)
// bias: [B, L, L] f32 ; out: [B*L, 768] bf16
__global__ __launch_bounds__(256, 2)
void attn_kernel(const unsigned short* __restrict__ qkv,
                 const float* __restrict__ bias,
                 unsigned short* __restrict__ out) {
    const int L = 1024, TD = 2304, HD = 96;
    const int qt = blockIdx.x, h = blockIdx.y, b = blockIdx.z;
    const int tid = threadIdx.x, lane = tid & 63, wid = tid >> 6;
    const int l15 = lane & 15, lq = lane >> 4;
    const int q0 = qt * 64;
    const float scale = 0.10206207261596576f; // 1/sqrt(96)

    __shared__ unsigned short Ks[64][104];
    __shared__ unsigned short Vt[96][72];
    __shared__ unsigned short Ps[4][16][72];

    // Q fragments stay in registers for the whole block
    bf16x8 qf[3];
    const int qrow = q0 + wid * 16 + l15;
#pragma unroll
    for (int kc = 0; kc < 3; kc++)
        qf[kc] = *(const bf16x8*)(qkv + (size_t)(b * L + qrow) * TD + h * HD + kc * 32 + lq * 8);

    f32x4 o[6];
#pragma unroll
    for (int df = 0; df < 6; df++) o[df] = 0.0f;
    float mrow[4] = {-1e30f, -1e30f, -1e30f, -1e30f};
    float lrow[4] = {0.f, 0.f, 0.f, 0.f};

    for (int kv0 = 0; kv0 < L; kv0 += 64) {
        // stage K tile [64][96]
#pragma unroll
        for (int i = 0; i < 3; i++) {
            int c = i * 256 + tid;          // 0..767
            int row = c / 12, cc = c % 12;  // 12 x 16B chunks per row
            *(f32x4*)&Ks[row][cc * 8] =
                *(const f32x4*)(qkv + (size_t)(b * L + kv0 + row) * TD + 768 + h * HD + cc * 8);
        }
        // stage V transposed: Vt[d][m]
#pragma unroll
        for (int i = 0; i < 3; i++) {
            int dblk = i * 4 + wid;  // 0..11
            int m = lane;
            u16x8 v = *(const u16x8*)(qkv + (size_t)(b * L + kv0 + m) * TD + 1536 + h * HD + dblk * 8);
#pragma unroll
            for (int j = 0; j < 8; j++) Vt[dblk * 8 + j][m] = v[j];
        }
        __syncthreads();

        // S = Q K^T  (wave computes its 16 q-rows x 64 kv-cols)
        f32x4 s[4];
#pragma unroll
        for (int nf = 0; nf < 4; nf++) s[nf] = 0.0f;
#pragma unroll
        for (int kc = 0; kc < 3; kc++) {
#pragma unroll
            for (int nf = 0; nf < 4; nf++) {
                bf16x8 kf = *(const bf16x8*)&Ks[nf * 16 + l15][kc * 32 + lq * 8];
                s[nf] = __builtin_amdgcn_mfma_f32_16x16x32_bf16(qf[kc], kf, s[nf], 0, 0, 0);
            }
        }
        // scale + bias
#pragma unroll
        for (int nf = 0; nf < 4; nf++) {
            int colg = kv0 + nf * 16 + l15;
#pragma unroll
            for (int r = 0; r < 4; r++) {
                int rowg = q0 + wid * 16 + lq * 4 + r;
                s[nf][r] = s[nf][r] * scale + bias[((size_t)b * L + rowg) * L + colg];
            }
        }
        // online softmax (row r of this quarter lives in 16 lanes: xor-reduce 1,2,4,8)
        float pm[4];
#pragma unroll
        for (int r = 0; r < 4; r++) {
            float mx = fmaxf(fmaxf(s[0][r], s[1][r]), fmaxf(s[2][r], s[3][r]));
#pragma unroll
            for (int d = 1; d < 16; d <<= 1) mx = fmaxf(mx, __shfl_xor(mx, d, 64));
            pm[r] = mx;
        }
        float alpha[4];
#pragma unroll
        for (int r = 0; r < 4; r++) {
            float mn = fmaxf(mrow[r], pm[r]);
            alpha[r] = __expf(mrow[r] - mn);
            mrow[r] = mn;
        }
        float rs[4] = {0.f, 0.f, 0.f, 0.f};
#pragma unroll
        for (int nf = 0; nf < 4; nf++)
#pragma unroll
            for (int r = 0; r < 4; r++) {
                float p = __expf(s[nf][r] - mrow[r]);
                s[nf][r] = p;
                rs[r] += p;
            }
#pragma unroll
        for (int r = 0; r < 4; r++) {
#pragma unroll
            for (int d = 1; d < 16; d <<= 1) rs[r] += __shfl_xor(rs[r], d, 64);
            lrow[r] = lrow[r] * alpha[r] + rs[r];
        }
        // P -> LDS (C-layout -> A-layout re-shape), bf16
#pragma unroll
        for (int nf = 0; nf < 4; nf++)
#pragma unroll
            for (int r = 0; r < 4; r++)
                Ps[wid][lq * 4 + r][nf * 16 + l15] = f2b(s[nf][r]);
        // rescale O
#pragma unroll
        for (int df = 0; df < 6; df++)
#pragma unroll
            for (int r = 0; r < 4; r++) o[df][r] *= alpha[r];
        // make P writes visible to the wave's own reads
        asm volatile("s_waitcnt lgkmcnt(0)" ::: "memory");
        // O += P V
#pragma unroll
        for (int kc = 0; kc < 2; kc++) {
            bf16x8 pf = *(const bf16x8*)&Ps[wid][l15][kc * 32 + lq * 8];
#pragma unroll
            for (int df = 0; df < 6; df++) {
                bf16x8 vf = *(const bf16x8*)&Vt[df * 16 + l15][kc * 32 + lq * 8];
                o[df] = __builtin_amdgcn_mfma_f32_16x16x32_bf16(pf, vf, o[df], 0, 0, 0);
            }
        }
        __syncthreads();
    }
    // normalize + write [B*L, 768]
#pragma unroll
    for (int r = 0; r < 4; r++) {
        float inv = 1.0f / lrow[r];
        int rowg = q0 + wid * 16 + lq * 4 + r;
#pragma unroll
        for (int df = 0; df < 6; df++)
            out[((size_t)b * L + rowg) * 768 + h * 96 + df * 16 + l15] = f2b(o[df][r] * inv);
    }
}

// ---------------- residual + layernorm ----------------
// out_f = LN(x + res) (f32), optionally also bf16 copy
template <int WRITE_B>
__global__ __launch_bounds__(256, 4)
void ln_kernel(const float* __restrict__ x, const float* __restrict__ res,
               const float* __restrict__ g, const float* __restrict__ bvec,
               float* __restrict__ outf, unsigned short* __restrict__ outb) {
    const int Dm = 768;
    int row = blockIdx.x;
    const float* xr = x + (size_t)row * Dm;
    const float* rr = res + (size_t)row * Dm;
    int tid = threadIdx.x;
    float v[3];
    float sum = 0.f, sq = 0.f;
#pragma unroll
    for (int j = 0; j < 3; j++) {
        int i = tid + j * 256;
        float t = xr[i] + rr[i];
        v[j] = t;
        sum += t;
        sq += t * t;
    }
#pragma unroll
    for (int d = 1; d < 64; d <<= 1) {
        sum += __shfl_xor(sum, d, 64);
        sq += __shfl_xor(sq, d, 64);
    }
    __shared__ float ps[8];
    int lane = tid & 63, wid = tid >> 6;
    if (lane == 0) { ps[wid] = sum; ps[wid + 4] = sq; }
    __syncthreads();
    sum = ps[0] + ps[1] + ps[2] + ps[3];
    sq = ps[4] + ps[5] + ps[6] + ps[7];
    float mu = sum * (1.0f / 768.0f);
    float var = sq * (1.0f / 768.0f) - mu * mu;
    float rsg = rsqrtf(var + 1e-5f);
#pragma unroll
    for (int j = 0; j < 3; j++) {
        int i = tid + j * 256;
        float o = (v[j] - mu) * rsg * g[i] + bvec[i];
        outf[(size_t)row * Dm + i] = o;
        if constexpr (WRITE_B) outb[(size_t)row * Dm + i] = f2b(o);
    }
}

// ---------------- launch ----------------
extern "C" void kernel_launch(void* const* d_in, const int* in_sizes, int n_in,
                              void* d_out, int out_size, void* d_ws, size_t ws_size,
                              hipStream_t stream) {
    (void)in_sizes; (void)n_in; (void)out_size; (void)ws_size;
    const float* x         = (const float*)d_in[0];
    const float* attn_bias = (const float*)d_in[1];
    const float* in_proj_w = (const float*)d_in[2];
    const float* in_proj_b = (const float*)d_in[3];
    const float* out_w     = (const float*)d_in[4];
    const float* out_b     = (const float*)d_in[5];
    const float* ff1_w     = (const float*)d_in[6];
    const float* ff1_b     = (const float*)d_in[7];
    const float* ff2_w     = (const float*)d_in[8];
    const float* ff2_b     = (const float*)d_in[9];
    const float* ln1_g     = (const float*)d_in[10];
    const float* ln1_b     = (const float*)d_in[11];
    const float* ln2_g     = (const float*)d_in[12];
    const float* ln2_b     = (const float*)d_in[13];

    const int NTOK = 4096;        // B*L
    char* ws = (char*)d_ws;
    size_t off = 0;
    auto alloc = [&](size_t bytes) { void* p = ws + off; off += (bytes + 255) & ~(size_t)255; return p; };
    unsigned short* xb    = (unsigned short*)alloc((size_t)NTOK * 768 * 2);
    unsigned short* wqkv  = (unsigned short*)alloc((size_t)2304 * 768 * 2);
    unsigned short* wout  = (unsigned short*)alloc((size_t)768 * 768 * 2);
    unsigned short* wff1  = (unsigned short*)alloc((size_t)2048 * 768 * 2);
    unsigned short* wff2  = (unsigned short*)alloc((size_t)768 * 2048 * 2);
    unsigned short* qkvb  = (unsigned short*)alloc((size_t)NTOK * 2304 * 2);
    unsigned short* attnb = (unsigned short*)alloc((size_t)NTOK * 768 * 2);
    float*          aproj = (float*)alloc((size_t)NTOK * 768 * 4);
    float*          x1f   = (float*)alloc((size_t)NTOK * 768 * 4);
    unsigned short* x1b   = (unsigned short*)alloc((size_t)NTOK * 768 * 2);
    // aliases (lifetimes are disjoint):
    unsigned short* h1b  = qkvb;   // [4096,2048] bf16 (16.8MB) fits in qkv region (18.9MB)
    float*          ff2o = aproj;  // [4096,768] f32, aproj is dead after LN1

    // f32 -> bf16 conversions
    cvt_kernel<<<dim3((NTOK * 768 / 4) / 256), 256, 0, stream>>>(x, xb, NTOK * 768 / 4);
    cvt_kernel<<<dim3((2304 * 768 / 4) / 256), 256, 0, stream>>>(in_proj_w, wqkv, 2304 * 768 / 4);
    cvt_kernel<<<dim3((768 * 768 / 4) / 256), 256, 0, stream>>>(out_w, wout, 768 * 768 / 4);
    cvt_kernel<<<dim3((2048 * 768 / 4) / 256), 256, 0, stream>>>(ff1_w, wff1, 2048 * 768 / 4);
    cvt_kernel<<<dim3((768 * 2048 / 4) / 256), 256, 0, stream>>>(ff2_w, wff2, 768 * 2048 / 4);

    // qkv = x @ in_proj_w^T + b        [4096, 2304] bf16   grid 9x32 = 288
    gemm_pipe<128, 256, 0><<<dim3(2304 / 256, NTOK / 128), 512, 0, stream>>>(xb, wqkv, in_proj_b, qkvb, NTOK, 2304, 768);
    // attention                         [4096, 768] bf16
    attn_kernel<<<dim3(16, 8, 4), 256, 0, stream>>>(qkvb, attn_bias, attnb);
    // attn @ out_w^T + b               [4096, 768] f32     grid 6x32 = 192
    gemm_pipe<128, 128, 1><<<dim3(768 / 128, NTOK / 128), 512, 0, stream>>>(attnb, wout, out_b, aproj, NTOK, 768, 768);
    // x1 = LN1(x + aproj)              f32 + bf16
    ln_kernel<1><<<dim3(NTOK), 256, 0, stream>>>(x, aproj, ln1_g, ln1_b, x1f, x1b);
    // h = gelu(x1 @ ff1^T + b)         [4096, 2048] bf16   grid 8x32 = 256
    gemm_pipe<128, 256, 2><<<dim3(2048 / 256, NTOK / 128), 512, 0, stream>>>(x1b, wff1, ff1_b, h1b, NTOK, 2048, 768);
    // ff2 = h @ ff2^T + b              [4096, 768] f32     grid 6x32 = 192
    gemm_pipe<128, 128, 1><<<dim3(768 / 128, NTOK / 128), 512, 0, stream>>>(h1b, wff2, ff2_b, ff2o, NTOK, 768, 2048);
    // out = LN2(x1 + ff2)              f32 -> d_out
    ln_kernel<0><<<dim3(NTOK), 256, 0, stream>>>(x1f, ff2o, ln2_g, ln2_b, (float*)d_out, nullptr);
}